// Round 1
// baseline (1772.013 us; speedup 1.0000x reference)
//
#include <hip/hip_runtime.h>

#define FDIM 128
#define NRBF 20
constexpr float CUTOFF_F = 5.0f;
constexpr float PI_F = 3.14159265358979323846f;

// ---------------------------------------------------------------------------
// Init: out[0:N*F) = node_scalar, out[N*F:4*N*F) = node_vector  (float4 copy)
// ---------------------------------------------------------------------------
__global__ __launch_bounds__(256) void init_out_kernel(
    const float* __restrict__ ns, const float* __restrict__ nv,
    float* __restrict__ out, int n1, int ntot) {
  const float4* s4 = (const float4*)ns;
  const float4* v4 = (const float4*)nv;
  float4* o4 = (float4*)out;
  int q1 = n1 >> 2, qt = ntot >> 2;
  for (int i = blockIdx.x * blockDim.x + threadIdx.x; i < qt;
       i += gridDim.x * blockDim.x) {
    o4[i] = (i < q1) ? s4[i] : v4[i - q1];
  }
}

// ---------------------------------------------------------------------------
// GEMM: C[M x Ncols] = act(A[M x 128] @ W[128 x Ncols] + bias)
// 64-row x 128-col tile per block, 256 threads, 4x8 outputs per thread.
// ---------------------------------------------------------------------------
template <int SILU>
__global__ __launch_bounds__(256) void gemm_k128(
    const float* __restrict__ A, const float* __restrict__ W,
    const float* __restrict__ bias, float* __restrict__ C, int M, int Ncols) {
  __shared__ float As[64][FDIM + 4];  // +4 pad: kills row-bank aliasing
  const int row0 = blockIdx.x * 64;
  const int col0 = blockIdx.y * 128;
  const int t = threadIdx.x;

  // Stage A tile (64x128 f32) as float4
  for (int i = t; i < 64 * 32; i += 256) {
    int r = i >> 5;
    int cc = (i & 31) << 2;
    int gr = row0 + r;
    float4 v = make_float4(0.f, 0.f, 0.f, 0.f);
    if (gr < M) v = *(const float4*)&A[(size_t)gr * FDIM + cc];
    *(float4*)&As[r][cc] = v;
  }
  __syncthreads();

  const int tx = t & 15;   // col group (8 cols)
  const int ty = t >> 4;   // row group (4 rows)
  const int c0 = col0 + tx * 8;
  const int r0 = ty * 4;

  float acc[4][8];
#pragma unroll
  for (int r = 0; r < 4; ++r)
#pragma unroll
    for (int c = 0; c < 8; ++c) acc[r][c] = 0.f;

#pragma unroll 4
  for (int k = 0; k < FDIM; ++k) {
    const float* wr = W + (size_t)k * Ncols + c0;
    float4 wa = *(const float4*)wr;
    float4 wb = *(const float4*)(wr + 4);
    float w[8] = {wa.x, wa.y, wa.z, wa.w, wb.x, wb.y, wb.z, wb.w};
    float a[4];
#pragma unroll
    for (int r = 0; r < 4; ++r) a[r] = As[r0 + r][k];
#pragma unroll
    for (int r = 0; r < 4; ++r)
#pragma unroll
      for (int c = 0; c < 8; ++c) acc[r][c] = fmaf(a[r], w[c], acc[r][c]);
  }

#pragma unroll
  for (int r = 0; r < 4; ++r) {
    int gr = row0 + r0 + r;
    if (gr >= M) continue;
    float v[8];
#pragma unroll
    for (int c = 0; c < 8; ++c) {
      float x = acc[r][c] + bias[c0 + c];
      if (SILU) x = x / (1.f + __expf(-x));
      v[c] = x;
    }
    float* crow = C + (size_t)gr * Ncols + c0;
    *(float4*)crow = make_float4(v[0], v[1], v[2], v[3]);
    *(float4*)(crow + 4) = make_float4(v[4], v[5], v[6], v[7]);
  }
}

// ---------------------------------------------------------------------------
// Edge kernel: one block (128 threads) per edge iteration, thread j owns
// columns {j, j+128, j+256}. Wr held in registers across the grid-stride loop.
// ---------------------------------------------------------------------------
__global__ __launch_bounds__(128) void edge_kernel(
    const float* __restrict__ adj, const float* __restrict__ atom,
    const float* __restrict__ nvec, const float* __restrict__ Wr,
    const float* __restrict__ br, float* __restrict__ out_s,
    float* __restrict__ out_v, int E) {
  const int j = threadIdx.x;

  // Persist Wr columns in registers: 60 VGPRs
  float wr0[NRBF], wr1[NRBF], wr2[NRBF];
#pragma unroll
  for (int n = 0; n < NRBF; ++n) {
    wr0[n] = Wr[n * 384 + j];
    wr1[n] = Wr[n * 384 + 128 + j];
    wr2[n] = Wr[n * 384 + 256 + j];
  }
  const float brj0 = br[j], brj1 = br[j + 128], brj2 = br[j + 256];

  for (int e = blockIdx.x; e < E; e += gridDim.x) {
    const float* arow6 = adj + (size_t)e * 6;
    int dst = (int)arow6[0];
    int src = (int)arow6[1];
    float rx = arow6[2], ry = arow6[3], rz = arow6[4];
    float d = arow6[5];

    float x = d * (PI_F / CUTOFF_F);
    float sx = sinf(x), cx = cosf(x);
    float twoc = 2.f * cx;
    float sprev = 0.f, scur = sx;  // sin(1*x)
    float a0 = 0.f, a1 = 0.f, a2 = 0.f;
#pragma unroll
    for (int n = 0; n < NRBF; ++n) {
      a0 = fmaf(scur, wr0[n], a0);
      a1 = fmaf(scur, wr1[n], a1);
      a2 = fmaf(scur, wr2[n], a2);
      float nxt = fmaf(twoc, scur, -sprev);  // sin((n+2)x)
      sprev = scur;
      scur = nxt;
    }
    float invd = 1.f / d;
    float cut = (d < CUTOFF_F) ? 0.5f * (cx + 1.f) : 0.f;
    float w0 = (a0 * invd + brj0) * cut;
    float w1 = (a1 * invd + brj1) * cut;
    float w2 = (a2 * invd + brj2) * cut;

    const float* arow = atom + (size_t)src * 384;
    float s1 = arow[j] * w0;
    float s2 = arow[j + 128] * w1;
    float s3 = arow[j + 256] * w2;

    unsafeAtomicAdd(out_s + (size_t)dst * FDIM + j, s2);

    float rhx = rx * invd, rhy = ry * invd, rhz = rz * invd;
    const float* vrow = nvec + (size_t)src * 384 + j * 3;
    float mv0 = fmaf(vrow[0], s1, s3 * rhx);
    float mv1 = fmaf(vrow[1], s1, s3 * rhy);
    float mv2 = fmaf(vrow[2], s1, s3 * rhz);

    float* vout = out_v + (size_t)dst * 384 + j * 3;
    unsafeAtomicAdd(vout + 0, mv0);
    unsafeAtomicAdd(vout + 1, mv1);
    unsafeAtomicAdd(vout + 2, mv2);
  }
}

// ---------------------------------------------------------------------------
extern "C" void kernel_launch(void* const* d_in, const int* in_sizes, int n_in,
                              void* d_out, int out_size, void* d_ws,
                              size_t ws_size, hipStream_t stream) {
  const float* node_scalar = (const float*)d_in[0];
  const float* node_vector = (const float*)d_in[1];
  const float* adj = (const float*)d_in[2];
  const float* W1 = (const float*)d_in[3];
  const float* b1 = (const float*)d_in[4];
  const float* W2 = (const float*)d_in[5];
  const float* b2 = (const float*)d_in[6];
  const float* Wr = (const float*)d_in[7];
  const float* br = (const float*)d_in[8];

  const int N = in_sizes[0] / FDIM;
  const int E = in_sizes[2] / 6;

  float* out = (float*)d_out;
  float* out_s = out;
  float* out_v = out + (size_t)N * FDIM;

  float* h = (float*)d_ws;                  // N x 128
  float* atom = h + (size_t)N * FDIM;       // N x 384

  // 1) out = [node_scalar, node_vector]
  init_out_kernel<<<2048, 256, 0, stream>>>(node_scalar, node_vector, out,
                                            N * FDIM, N * FDIM * 4);
  // 2) h = silu(ns @ W1 + b1)
  dim3 g1((N + 63) / 64, 1);
  gemm_k128<1><<<g1, 256, 0, stream>>>(node_scalar, W1, b1, h, N, 128);
  // 3) atom = h @ W2 + b2
  dim3 g2((N + 63) / 64, 3);
  gemm_k128<0><<<g2, 256, 0, stream>>>(h, W2, b2, atom, N, 384);
  // 4) edge scatter
  edge_kernel<<<8192, 128, 0, stream>>>(adj, atom, node_vector, Wr, br, out_s,
                                        out_v, E);
}

// Round 2
// 438.643 us; speedup vs baseline: 4.0398x; 4.0398x over previous
//
#include <hip/hip_runtime.h>

#define FDIM 128
#define NRBF 20
constexpr float CUTOFF_F = 5.0f;
constexpr float PI_F = 3.14159265358979323846f;

// ---------------------------------------------------------------------------
// GEMM: C[M x Ncols] = act(A[M x 128] @ W[128 x Ncols] + bias)
// 64-row x 128-col tile per block, 256 threads, 4x8 outputs per thread.
// ---------------------------------------------------------------------------
template <int SILU>
__global__ __launch_bounds__(256) void gemm_k128(
    const float* __restrict__ A, const float* __restrict__ W,
    const float* __restrict__ bias, float* __restrict__ C, int M, int Ncols) {
  __shared__ float As[64][FDIM + 4];
  const int row0 = blockIdx.x * 64;
  const int col0 = blockIdx.y * 128;
  const int t = threadIdx.x;

  for (int i = t; i < 64 * 32; i += 256) {
    int r = i >> 5;
    int cc = (i & 31) << 2;
    int gr = row0 + r;
    float4 v = make_float4(0.f, 0.f, 0.f, 0.f);
    if (gr < M) v = *(const float4*)&A[(size_t)gr * FDIM + cc];
    *(float4*)&As[r][cc] = v;
  }
  __syncthreads();

  const int tx = t & 15;
  const int ty = t >> 4;
  const int c0 = col0 + tx * 8;
  const int r0 = ty * 4;

  float acc[4][8];
#pragma unroll
  for (int r = 0; r < 4; ++r)
#pragma unroll
    for (int c = 0; c < 8; ++c) acc[r][c] = 0.f;

#pragma unroll 4
  for (int k = 0; k < FDIM; ++k) {
    const float* wr = W + (size_t)k * Ncols + c0;
    float4 wa = *(const float4*)wr;
    float4 wb = *(const float4*)(wr + 4);
    float w[8] = {wa.x, wa.y, wa.z, wa.w, wb.x, wb.y, wb.z, wb.w};
    float a[4];
#pragma unroll
    for (int r = 0; r < 4; ++r) a[r] = As[r0 + r][k];
#pragma unroll
    for (int r = 0; r < 4; ++r)
#pragma unroll
      for (int c = 0; c < 8; ++c) acc[r][c] = fmaf(a[r], w[c], acc[r][c]);
  }

#pragma unroll
  for (int r = 0; r < 4; ++r) {
    int gr = row0 + r0 + r;
    if (gr >= M) continue;
    float v[8];
#pragma unroll
    for (int c = 0; c < 8; ++c) {
      float x = acc[r][c] + bias[c0 + c];
      if (SILU) x = x / (1.f + __expf(-x));
      v[c] = x;
    }
    float* crow = C + (size_t)gr * Ncols + c0;
    *(float4*)crow = make_float4(v[0], v[1], v[2], v[3]);
    *(float4*)(crow + 4) = make_float4(v[4], v[5], v[6], v[7]);
  }
}

// ---------------------------------------------------------------------------
// CSR build: histogram -> scan -> scatter
// ---------------------------------------------------------------------------
__global__ __launch_bounds__(256) void hist_kernel(const float* __restrict__ adj,
                                                   int* __restrict__ counts,
                                                   int E) {
  int e = blockIdx.x * blockDim.x + threadIdx.x;
  if (e < E) {
    int dst = (int)adj[(size_t)e * 6];
    atomicAdd(&counts[dst], 1);
  }
}

__global__ __launch_bounds__(1024) void scan_kernel(const int* __restrict__ counts,
                                                    int* __restrict__ offs,
                                                    int* __restrict__ cursor,
                                                    int n) {
  __shared__ int sh[1024];
  __shared__ int sbase;
  const int tid = threadIdx.x;
  if (tid == 0) {
    sbase = 0;
    offs[0] = 0;
  }
  __syncthreads();
  for (int start = 0; start < n; start += 1024) {
    int i = start + tid;
    int v = (i < n) ? counts[i] : 0;
    sh[tid] = v;
    __syncthreads();
    for (int off = 1; off < 1024; off <<= 1) {
      int tv = (tid >= off) ? sh[tid - off] : 0;
      __syncthreads();
      sh[tid] += tv;
      __syncthreads();
    }
    int incl = sh[tid];
    int base = sbase;
    if (i < n) {
      offs[i + 1] = base + incl;
      cursor[i] = base + incl - v;  // exclusive offset
    }
    __syncthreads();
    if (tid == 0) sbase = base + sh[1023];
    __syncthreads();
  }
}

__global__ __launch_bounds__(256) void scatter_kernel(
    const float* __restrict__ adj, int* __restrict__ cursor,
    int* __restrict__ eids, int E) {
  int e = blockIdx.x * blockDim.x + threadIdx.x;
  if (e < E) {
    int dst = (int)adj[(size_t)e * 6];
    int p = atomicAdd(&cursor[dst], 1);
    eids[p] = e;
  }
}

// ---------------------------------------------------------------------------
// Per-dst accumulation: one block (128 threads) per node, no output atomics.
// ---------------------------------------------------------------------------
struct Geom {
  int src;
  float rx, ry, rz, d;
};

__device__ __forceinline__ Geom load_geom(const float* __restrict__ adj, int e) {
  const float* a = adj + (size_t)e * 6;
  Geom g;
  g.src = (int)a[1];
  g.rx = a[2];
  g.ry = a[3];
  g.rz = a[4];
  g.d = a[5];
  return g;
}

__global__ __launch_bounds__(128) void accum_kernel(
    const float* __restrict__ adj, const float* __restrict__ atom,
    const float* __restrict__ nvec, const float* __restrict__ Wr,
    const float* __restrict__ br, const float* __restrict__ ns,
    const float* __restrict__ nv, const int* __restrict__ offs,
    const int* __restrict__ eids, float* __restrict__ out_s,
    float* __restrict__ out_v) {
  const int d = blockIdx.x;
  const int j = threadIdx.x;

  float wr0[NRBF], wr1[NRBF], wr2[NRBF];
#pragma unroll
  for (int n = 0; n < NRBF; ++n) {
    wr0[n] = Wr[n * 384 + j];
    wr1[n] = Wr[n * 384 + 128 + j];
    wr2[n] = Wr[n * 384 + 256 + j];
  }
  const float brj0 = br[j], brj1 = br[j + 128], brj2 = br[j + 256];

  __shared__ int sh_eid[128];
  const int beg = offs[d];
  const int cnt = offs[d + 1] - beg;
  if (j < cnt && j < 128) sh_eid[j] = eids[beg + j];
  __syncthreads();
  if (j == 0) {  // insertion sort for stable accumulation order
    int m = cnt < 128 ? cnt : 128;
    for (int a = 1; a < m; ++a) {
      int key = sh_eid[a];
      int b = a - 1;
      while (b >= 0 && sh_eid[b] > key) {
        sh_eid[b + 1] = sh_eid[b];
        --b;
      }
      sh_eid[b + 1] = key;
    }
  }
  __syncthreads();

  float acc_s = 0.f, av0 = 0.f, av1 = 0.f, av2 = 0.f;

  // 2-deep geometry / 1-deep values software pipeline
  Geom g0, g1;
  float pa0 = 0, pa1 = 0, pa2 = 0, pv0 = 0, pv1 = 0, pv2 = 0;
  if (cnt > 0) g0 = load_geom(adj, sh_eid[0]);
  if (cnt > 1) g1 = load_geom(adj, (1 < 128) ? sh_eid[1] : eids[beg + 1]);
  if (cnt > 0) {
    const float* ar = atom + (size_t)g0.src * 384;
    pa0 = ar[j];
    pa1 = ar[j + 128];
    pa2 = ar[j + 256];
    const float* vr = nvec + (size_t)g0.src * 384 + j * 3;
    pv0 = vr[0];
    pv1 = vr[1];
    pv2 = vr[2];
  }

  for (int t = 0; t < cnt; ++t) {
    Geom g2;
    if (t + 2 < cnt) {
      int e2 = (t + 2 < 128) ? sh_eid[t + 2] : eids[beg + t + 2];
      g2 = load_geom(adj, e2);
    }
    float na0 = 0, na1 = 0, na2 = 0, nv0 = 0, nv1 = 0, nv2 = 0;
    if (t + 1 < cnt) {
      const float* ar = atom + (size_t)g1.src * 384;
      na0 = ar[j];
      na1 = ar[j + 128];
      na2 = ar[j + 256];
      const float* vr = nvec + (size_t)g1.src * 384 + j * 3;
      nv0 = vr[0];
      nv1 = vr[1];
      nv2 = vr[2];
    }

    // compute on g0 / pa / pv
    float x = g0.d * (PI_F / CUTOFF_F);
    float sx, cx;
    __sincosf(x, &sx, &cx);
    float twoc = 2.f * cx;
    float sprev = 0.f, scur = sx;
    float a0 = 0.f, a1 = 0.f, a2 = 0.f;
#pragma unroll
    for (int n = 0; n < NRBF; ++n) {
      a0 = fmaf(scur, wr0[n], a0);
      a1 = fmaf(scur, wr1[n], a1);
      a2 = fmaf(scur, wr2[n], a2);
      float nxt = fmaf(twoc, scur, -sprev);
      sprev = scur;
      scur = nxt;
    }
    float invd = 1.f / g0.d;
    float cut = (g0.d < CUTOFF_F) ? 0.5f * (cx + 1.f) : 0.f;
    float w0 = (a0 * invd + brj0) * cut;
    float w1 = (a1 * invd + brj1) * cut;
    float w2 = (a2 * invd + brj2) * cut;

    float s1 = pa0 * w0;
    float s2 = pa1 * w1;
    float s3 = pa2 * w2;

    acc_s += s2;
    float rhx = g0.rx * invd, rhy = g0.ry * invd, rhz = g0.rz * invd;
    av0 = fmaf(pv0, s1, fmaf(s3, rhx, av0));
    av1 = fmaf(pv1, s1, fmaf(s3, rhy, av1));
    av2 = fmaf(pv2, s1, fmaf(s3, rhz, av2));

    g0 = g1;
    g1 = g2;
    pa0 = na0;
    pa1 = na1;
    pa2 = na2;
    pv0 = nv0;
    pv1 = nv1;
    pv2 = nv2;
  }

  out_s[(size_t)d * FDIM + j] = ns[(size_t)d * FDIM + j] + acc_s;
  float* vo = out_v + (size_t)d * 384 + j * 3;
  const float* vi = nv + (size_t)d * 384 + j * 3;
  vo[0] = vi[0] + av0;
  vo[1] = vi[1] + av1;
  vo[2] = vi[2] + av2;
}

// ---------------------------------------------------------------------------
extern "C" void kernel_launch(void* const* d_in, const int* in_sizes, int n_in,
                              void* d_out, int out_size, void* d_ws,
                              size_t ws_size, hipStream_t stream) {
  const float* node_scalar = (const float*)d_in[0];
  const float* node_vector = (const float*)d_in[1];
  const float* adj = (const float*)d_in[2];
  const float* W1 = (const float*)d_in[3];
  const float* b1 = (const float*)d_in[4];
  const float* W2 = (const float*)d_in[5];
  const float* b2 = (const float*)d_in[6];
  const float* Wr = (const float*)d_in[7];
  const float* br = (const float*)d_in[8];

  const int N = in_sizes[0] / FDIM;
  const int E = in_sizes[2] / 6;

  float* out = (float*)d_out;
  float* out_s = out;
  float* out_v = out + (size_t)N * FDIM;

  // workspace layout
  float* atom = (float*)d_ws;                      // N x 384
  int* counts = (int*)(atom + (size_t)N * 384);    // N
  int* offs = counts + N;                          // N + 1
  int* cursor = offs + N + 1;                      // N
  int* eids = cursor + N;                          // E

  // h lives in d_out (fully overwritten by accum_kernel at the end)
  float* h = out_s;  // N x 128

  hipMemsetAsync(counts, 0, (size_t)N * sizeof(int), stream);
  hist_kernel<<<(E + 255) / 256, 256, 0, stream>>>(adj, counts, E);
  scan_kernel<<<1, 1024, 0, stream>>>(counts, offs, cursor, N);
  scatter_kernel<<<(E + 255) / 256, 256, 0, stream>>>(adj, cursor, eids, E);

  dim3 g1((N + 63) / 64, 1);
  gemm_k128<1><<<g1, 256, 0, stream>>>(node_scalar, W1, b1, h, N, 128);
  dim3 g2((N + 63) / 64, 3);
  gemm_k128<0><<<g2, 256, 0, stream>>>(h, W2, b2, atom, N, 384);

  accum_kernel<<<N, 128, 0, stream>>>(adj, atom, node_vector, Wr, br,
                                      node_scalar, node_vector, offs, eids,
                                      out_s, out_v);
}

// Round 3
// 344.882 us; speedup vs baseline: 5.1380x; 1.2719x over previous
//
#include <hip/hip_runtime.h>

#define FDIM 128
#define NRBF 20
#define REC_W 16  // u32 words per edge record (64B)
constexpr float CUTOFF_F = 5.0f;
constexpr float PI_F = 3.14159265358979323846f;

typedef _Float16 h2 __attribute__((ext_vector_type(2)));

__device__ __forceinline__ uint packh(float a, float b) {
  union { _Float16 h[2]; uint u; } x;
  x.h[0] = (_Float16)a;
  x.h[1] = (_Float16)b;
  return x.u;
}
__device__ __forceinline__ float h_lo(uint w) {
  union { uint u; _Float16 h[2]; } x;
  x.u = w;
  return (float)x.h[0];
}
__device__ __forceinline__ float h_hi(uint w) {
  union { uint u; _Float16 h[2]; } x;
  x.u = w;
  return (float)x.h[1];
}
__device__ __forceinline__ float us2f(ushort u) {
  union { ushort s; _Float16 h; } x;
  x.s = u;
  return (float)x.h;
}
__device__ __forceinline__ float dot2(uint cw, h2 w, float acc) {
#if __has_builtin(__builtin_amdgcn_fdot2)
  h2 c = __builtin_bit_cast(h2, cw);
  return __builtin_amdgcn_fdot2(c, w, acc, false);
#else
  return fmaf(h_hi(cw), (float)w[1], fmaf(h_lo(cw), (float)w[0], acc));
#endif
}

// ---------------------------------------------------------------------------
// GEMM: C = act(A[Mx128] @ W[128xN] + bias); OUTH=1 stores _Float16.
// ---------------------------------------------------------------------------
template <int SILU, int OUTH>
__global__ __launch_bounds__(256) void gemm_k128(
    const float* __restrict__ A, const float* __restrict__ W,
    const float* __restrict__ bias, float* __restrict__ Cf,
    ushort* __restrict__ Ch, int M, int Ncols) {
  __shared__ float As[64][FDIM + 4];
  const int row0 = blockIdx.x * 64;
  const int col0 = blockIdx.y * 128;
  const int t = threadIdx.x;

  for (int i = t; i < 64 * 32; i += 256) {
    int r = i >> 5;
    int cc = (i & 31) << 2;
    int gr = row0 + r;
    float4 v = make_float4(0.f, 0.f, 0.f, 0.f);
    if (gr < M) v = *(const float4*)&A[(size_t)gr * FDIM + cc];
    *(float4*)&As[r][cc] = v;
  }
  __syncthreads();

  const int tx = t & 15;
  const int ty = t >> 4;
  const int c0 = col0 + tx * 8;
  const int r0 = ty * 4;

  float acc[4][8];
#pragma unroll
  for (int r = 0; r < 4; ++r)
#pragma unroll
    for (int c = 0; c < 8; ++c) acc[r][c] = 0.f;

#pragma unroll 4
  for (int k = 0; k < FDIM; ++k) {
    const float* wr = W + (size_t)k * Ncols + c0;
    float4 wa = *(const float4*)wr;
    float4 wb = *(const float4*)(wr + 4);
    float w[8] = {wa.x, wa.y, wa.z, wa.w, wb.x, wb.y, wb.z, wb.w};
    float a[4];
#pragma unroll
    for (int r = 0; r < 4; ++r) a[r] = As[r0 + r][k];
#pragma unroll
    for (int r = 0; r < 4; ++r)
#pragma unroll
      for (int c = 0; c < 8; ++c) acc[r][c] = fmaf(a[r], w[c], acc[r][c]);
  }

#pragma unroll
  for (int r = 0; r < 4; ++r) {
    int gr = row0 + r0 + r;
    if (gr >= M) continue;
    float v[8];
#pragma unroll
    for (int c = 0; c < 8; ++c) {
      float x = acc[r][c] + bias[c0 + c];
      if (SILU) x = x / (1.f + __expf(-x));
      v[c] = x;
    }
    if (OUTH) {
      union { ushort s[8]; uint4 q; } p;
#pragma unroll
      for (int c = 0; c < 8; ++c) {
        union { _Float16 h; ushort s; } cv;
        cv.h = (_Float16)v[c];
        p.s[c] = cv.s;
      }
      *(uint4*)&Ch[(size_t)gr * Ncols + c0] = p.q;
    } else {
      float* crow = Cf + (size_t)gr * Ncols + c0;
      *(float4*)crow = make_float4(v[0], v[1], v[2], v[3]);
      *(float4*)(crow + 4) = make_float4(v[4], v[5], v[6], v[7]);
    }
  }
}

// ---------------------------------------------------------------------------
// CSR build
// ---------------------------------------------------------------------------
__global__ __launch_bounds__(256) void hist_kernel(const float* __restrict__ adj,
                                                   int* __restrict__ counts,
                                                   int E) {
  int e = blockIdx.x * blockDim.x + threadIdx.x;
  if (e < E) atomicAdd(&counts[(int)adj[(size_t)e * 6]], 1);
}

__global__ __launch_bounds__(1024) void scan_kernel(
    const int* __restrict__ counts, int* __restrict__ offs,
    int* __restrict__ cursor, int n) {
  __shared__ int part[1024];
  const int tid = threadIdx.x;
  const int CH = (n + 1023) >> 10;
  const int b = tid * CH;
  const int e = min(b + CH, n);
  int s = 0;
  for (int i = b; i < e; ++i) s += counts[i];
  part[tid] = s;
  __syncthreads();
  // Hillis-Steele inclusive scan on 1024 partials
  for (int off = 1; off < 1024; off <<= 1) {
    int v = (tid >= off) ? part[tid - off] : 0;
    __syncthreads();
    part[tid] += v;
    __syncthreads();
  }
  int run = part[tid] - s;  // exclusive
  if (tid == 0) offs[0] = 0;
  for (int i = b; i < e; ++i) {
    int c = counts[i];
    cursor[i] = run;
    run += c;
    offs[i + 1] = run;
  }
}

// ---------------------------------------------------------------------------
// Edge prep: scatter eid + build 64B record:
// w0=src, w1=(rhx,rhy), w2=(rhz,cut), w3..12=(c0,c1)..(c18,c19), c_n=sin(nx)*invd*cut
// ---------------------------------------------------------------------------
__global__ __launch_bounds__(256) void edge_prep(const float* __restrict__ adj,
                                                 int* __restrict__ cursor,
                                                 int* __restrict__ eids,
                                                 uint* __restrict__ rec, int E) {
  int e = blockIdx.x * blockDim.x + threadIdx.x;
  if (e >= E) return;
  const float* a = adj + (size_t)e * 6;
  int dst = (int)a[0];
  int src = (int)a[1];
  float rx = a[2], ry = a[3], rz = a[4], d = a[5];

  int p = atomicAdd(&cursor[dst], 1);
  eids[p] = e;

  float x = d * (PI_F / CUTOFF_F);
  float sx, cx;
  __sincosf(x, &sx, &cx);
  float invd = 1.f / d;
  float cut = (d < CUTOFF_F) ? 0.5f * (cx + 1.f) : 0.f;
  float sc = invd * cut;

  union { uint w[16]; uint4 q[4]; } R;
  R.w[0] = (uint)src;
  R.w[1] = packh(rx * invd, ry * invd);
  R.w[2] = packh(rz * invd, cut);
  float twoc = 2.f * cx;
  float sprev = 0.f, scur = sx;
  float c[NRBF];
#pragma unroll
  for (int n = 0; n < NRBF; ++n) {
    c[n] = scur * sc;
    float nxt = fmaf(twoc, scur, -sprev);
    sprev = scur;
    scur = nxt;
  }
#pragma unroll
  for (int m = 0; m < 10; ++m) R.w[3 + m] = packh(c[2 * m], c[2 * m + 1]);
  R.w[13] = 0;
  R.w[14] = 0;
  R.w[15] = 0;
  uint4* o = (uint4*)(rec + ((size_t)e << 4));
#pragma unroll
  for (int m = 0; m < 4; ++m) o[m] = R.q[m];
}

// ---------------------------------------------------------------------------
// Per-dst accumulation, records via scalar loads, f16 dot2.
// ---------------------------------------------------------------------------
__global__ __launch_bounds__(128) void accum_kernel(
    const uint* __restrict__ rec, const ushort* __restrict__ atomh,
    const float* __restrict__ nvec, const float* __restrict__ Wr,
    const float* __restrict__ br, const float* __restrict__ ns,
    const int* __restrict__ offs, const int* __restrict__ eids,
    float* __restrict__ out_s, float* __restrict__ out_v) {
  const int d = blockIdx.x;
  const int j = threadIdx.x;

  // Wr columns as packed half2: 30 VGPRs
  h2 wp0[10], wp1[10], wp2[10];
#pragma unroll
  for (int m = 0; m < 10; ++m) {
    wp0[m] = h2{(_Float16)Wr[(2 * m) * 384 + j], (_Float16)Wr[(2 * m + 1) * 384 + j]};
    wp1[m] = h2{(_Float16)Wr[(2 * m) * 384 + 128 + j], (_Float16)Wr[(2 * m + 1) * 384 + 128 + j]};
    wp2[m] = h2{(_Float16)Wr[(2 * m) * 384 + 256 + j], (_Float16)Wr[(2 * m + 1) * 384 + 256 + j]};
  }
  const float brj0 = br[j], brj1 = br[j + 128], brj2 = br[j + 256];

  __shared__ int sh_e[128], sh_s[128];
  const int beg = offs[d];
  const int cnt = offs[d + 1] - beg;
  const int m = cnt < 128 ? cnt : 128;
  if (j < m) sh_e[j] = eids[beg + j];
  __syncthreads();
  if (j < m) {  // parallel rank sort (eids unique)
    int v = sh_e[j];
    int r = 0;
    for (int u = 0; u < m; ++u) r += (sh_e[u] < v);
    sh_s[r] = v;
  }
  __syncthreads();

#define EID(t) ((t) < 128 ? sh_s[(t)] : eids[beg + (t)])
#define LOADREC(R, t)                                                      \
  {                                                                        \
    int eu = __builtin_amdgcn_readfirstlane(EID(t));                       \
    const uint* p = rec + ((size_t)(uint)eu << 4);                         \
    _Pragma("unroll") for (int w_ = 0; w_ < 13; ++w_) R[w_] = p[w_];       \
  }

  float acc_s = 0.f, av0 = 0.f, av1 = 0.f, av2 = 0.f;

  uint r_cur[13], r_nxt[13];
  float pa0 = 0, pa1 = 0, pa2 = 0, pv0 = 0, pv1 = 0, pv2 = 0;
  if (cnt > 0) LOADREC(r_cur, 0);
  if (cnt > 1) LOADREC(r_nxt, 1);
  if (cnt > 0) {
    int src = (int)r_cur[0];
    const ushort* ab = atomh + (size_t)src * 384;
    pa0 = us2f(ab[j]);
    pa1 = us2f(ab[j + 128]);
    pa2 = us2f(ab[j + 256]);
    const float* vb = nvec + (size_t)src * 384 + j * 3;
    pv0 = vb[0];
    pv1 = vb[1];
    pv2 = vb[2];
  }

  for (int t = 0; t < cnt; ++t) {
    // issue next values
    float na0 = 0, na1 = 0, na2 = 0, nv0 = 0, nv1 = 0, nv2 = 0;
    if (t + 1 < cnt) {
      int src = (int)r_nxt[0];
      const ushort* ab = atomh + (size_t)src * 384;
      na0 = us2f(ab[j]);
      na1 = us2f(ab[j + 128]);
      na2 = us2f(ab[j + 256]);
      const float* vb = nvec + (size_t)src * 384 + j * 3;
      nv0 = vb[0];
      nv1 = vb[1];
      nv2 = vb[2];
    }
    // issue next-next record
    uint r_n2[13];
    if (t + 2 < cnt) LOADREC(r_n2, t + 2);

    // compute with r_cur
    float rhx = h_lo(r_cur[1]), rhy = h_hi(r_cur[1]);
    float rhz = h_lo(r_cur[2]), cut = h_hi(r_cur[2]);
    float w0 = cut * brj0, w1 = cut * brj1, w2 = cut * brj2;
#pragma unroll
    for (int q = 0; q < 10; ++q) {
      w0 = dot2(r_cur[3 + q], wp0[q], w0);
      w1 = dot2(r_cur[3 + q], wp1[q], w1);
      w2 = dot2(r_cur[3 + q], wp2[q], w2);
    }
    float s1 = pa0 * w0;
    float s2 = pa1 * w1;
    float s3 = pa2 * w2;
    acc_s += s2;
    av0 = fmaf(pv0, s1, fmaf(s3, rhx, av0));
    av1 = fmaf(pv1, s1, fmaf(s3, rhy, av1));
    av2 = fmaf(pv2, s1, fmaf(s3, rhz, av2));

#pragma unroll
    for (int w_ = 0; w_ < 13; ++w_) {
      r_cur[w_] = r_nxt[w_];
      r_nxt[w_] = r_n2[w_];
    }
    pa0 = na0; pa1 = na1; pa2 = na2;
    pv0 = nv0; pv1 = nv1; pv2 = nv2;
  }

  out_s[(size_t)d * FDIM + j] = ns[(size_t)d * FDIM + j] + acc_s;
  float* vo = out_v + (size_t)d * 384 + j * 3;
  const float* vi = nvec + (size_t)d * 384 + j * 3;
  vo[0] = vi[0] + av0;
  vo[1] = vi[1] + av1;
  vo[2] = vi[2] + av2;
#undef EID
#undef LOADREC
}

// ---------------------------------------------------------------------------
extern "C" void kernel_launch(void* const* d_in, const int* in_sizes, int n_in,
                              void* d_out, int out_size, void* d_ws,
                              size_t ws_size, hipStream_t stream) {
  const float* node_scalar = (const float*)d_in[0];
  const float* node_vector = (const float*)d_in[1];
  const float* adj = (const float*)d_in[2];
  const float* W1 = (const float*)d_in[3];
  const float* b1 = (const float*)d_in[4];
  const float* W2 = (const float*)d_in[5];
  const float* b2 = (const float*)d_in[6];
  const float* Wr = (const float*)d_in[7];
  const float* br = (const float*)d_in[8];

  const int N = in_sizes[0] / FDIM;
  const int E = in_sizes[2] / 6;

  float* out = (float*)d_out;
  float* out_s = out;
  float* out_v = out + (size_t)N * FDIM;

  // workspace: atomh(f16 N*384) | rec(E*16 u32) | counts | offs | cursor | eids
  ushort* atomh = (ushort*)d_ws;
  uint* rec = (uint*)(atomh + (size_t)N * 384);
  int* counts = (int*)(rec + ((size_t)E << 4));
  int* offs = counts + N;
  int* cursor = offs + N + 1;
  int* eids = cursor + N;

  float* h = out_s;  // N x 128, dead before accum writes out

  hipMemsetAsync(counts, 0, (size_t)N * sizeof(int), stream);
  hist_kernel<<<(E + 255) / 256, 256, 0, stream>>>(adj, counts, E);
  scan_kernel<<<1, 1024, 0, stream>>>(counts, offs, cursor, N);
  edge_prep<<<(E + 255) / 256, 256, 0, stream>>>(adj, cursor, eids, rec, E);

  dim3 g1((N + 63) / 64, 1);
  gemm_k128<1, 0><<<g1, 256, 0, stream>>>(node_scalar, W1, b1, h, nullptr, N, 128);
  dim3 g2((N + 63) / 64, 3);
  gemm_k128<0, 1><<<g2, 256, 0, stream>>>(h, W2, b2, nullptr, atomh, N, 384);

  accum_kernel<<<N, 128, 0, stream>>>(rec, atomh, node_vector, Wr, br,
                                      node_scalar, offs, eids, out_s, out_v);
}